// Round 9
// baseline (252.095 us; speedup 1.0000x reference)
//
#include <hip/hip_runtime.h>
#include <math.h>

#define D_IN  128
#define H_DIM 64
#define D_OUT 40
#define BW_SHIFT 9            // bucket width = 512 nodes
#define BW_NODES 512
#define BINA_CHUNK 4096
#define BUCKET_CAP 9216       // fixed bucket capacity; mean 8192, sd ~90 -> +11 sigma

typedef unsigned int uint32;

__device__ __forceinline__ unsigned short f2bf(float v) {
    uint32 b = __float_as_uint(v);
    b += 0x7fffu + ((b >> 16) & 1u);      // RNE
    return (unsigned short)(b >> 16);
}
__device__ __forceinline__ float bf2f(unsigned short u) {
    return __uint_as_float(((uint32)u) << 16);
}

// ============ cursor init: gcursor[b] = b*CAP ============
__global__ void cursor_init_kernel(int* __restrict__ gcursor, int NBUCK) {
    int i = blockIdx.x * 256 + threadIdx.x;
    if (i < NBUCK) gcursor[i] = i * BUCKET_CAP;
}

// ============ Phase A: scatter packed edges into fixed bucket regions ============
__global__ __launch_bounds__(256) void binA_scatter_kernel(const int* __restrict__ src,
                                                           const int* __restrict__ dst,
                                                           int* __restrict__ gcursor,
                                                           uint32* __restrict__ binned,
                                                           int E, int NBUCK) {
    __shared__ int cnt[1024];
    __shared__ int lbase[1024];
    int t = threadIdx.x;
    for (int i = t; i < NBUCK; i += 256) cnt[i] = 0;
    __syncthreads();
    int e0 = blockIdx.x * BINA_CHUNK;
    int e1 = min(e0 + BINA_CHUNK, E);
    for (int e = e0 + t; e < e1; e += 256)
        atomicAdd(&cnt[dst[e] >> BW_SHIFT], 1);
    __syncthreads();
    for (int i = t; i < NBUCK; i += 256) {
        int c = cnt[i];
        lbase[i] = c ? atomicAdd(&gcursor[i], c) : 0;
        cnt[i] = 0;               // reuse as local cursor
    }
    __syncthreads();
    for (int e = e0 + t; e < e1; e += 256) {
        int d = dst[e];
        int bk = d >> BW_SHIFT;
        int p = lbase[bk] + atomicAdd(&cnt[bk], 1);
        binned[p] = (((uint32)(d & (BW_NODES - 1))) << 23) | (uint32)src[e];
    }
}

// ============ Phase B: stage bucket in LDS; deg/dinv/rows; csr written IN PLACE ============
__global__ __launch_bounds__(256) void phaseB_kernel(uint32* __restrict__ binned,
                                                     const int* __restrict__ gcur_end,
                                                     int* __restrict__ rows,
                                                     float* __restrict__ dinv,
                                                     int N) {
    __shared__ uint32 sedge[BUCKET_CAP];          // 36 KB
    __shared__ int deg[BW_NODES];
    __shared__ int sa[BW_NODES], sb[BW_NODES];
    __shared__ int cur[BW_NODES];
    int b = blockIdx.x;
    int node0 = b << BW_SHIFT;
    int nn = min(BW_NODES, N - node0);
    int base = b * BUCKET_CAP;
    int cnt = gcur_end[b] - base;
    int t = threadIdx.x;
    deg[t] = 0; deg[t + 256] = 0;
    __syncthreads();
    for (int e = t; e < cnt; e += 256) {
        uint32 v = binned[base + e];
        sedge[e] = v;
        atomicAdd(&deg[v >> 23], 1);
    }
    __syncthreads();
    for (int i = t; i < nn; i += 256)
        dinv[node0 + i] = rsqrtf(1.0f + (float)deg[i]);
    sa[t] = deg[t]; sa[t + 256] = deg[t + 256];
    __syncthreads();
    int* pa = sa; int* pb = sb;
    for (int off = 1; off < BW_NODES; off <<= 1) {
        for (int i = t; i < BW_NODES; i += 256)
            pb[i] = pa[i] + ((i >= off) ? pa[i - off] : 0);
        __syncthreads();
        int* tmp = pa; pa = pb; pb = tmp;
    }
    for (int i = t; i < BW_NODES; i += 256)
        cur[i] = (i ? pa[i - 1] : 0);
    __syncthreads();
    int* rb = rows + b * 513;
    for (int i = t; i < nn; i += 256)
        rb[i] = base + cur[i];
    if (t == 0) rb[nn] = base + cnt;
    __syncthreads();
    for (int e = t; e < cnt; e += 256) {
        uint32 v = sedge[e];
        int doff = v >> 23;
        int p = base + atomicAdd(&cur[doff], 1);
        binned[p] = v & 0x7FFFFFu;
    }
}

// ============ GEMM1: 4 threads/node x 16 cols; h1s = bf16(dinv * (x @ W1)) ============
__global__ __launch_bounds__(256) void gemm1_tn4(const float* __restrict__ x,
                                                 const float* __restrict__ W1,
                                                 const float* __restrict__ dinv,
                                                 unsigned short* __restrict__ h1s, int N) {
    __shared__ float sW[D_IN * H_DIM];      // 32 KB
    int t = threadIdx.x;
    for (int i = t; i < D_IN * H_DIM / 4; i += 256)
        reinterpret_cast<float4*>(sW)[i] = reinterpret_cast<const float4*>(W1)[i];
    __syncthreads();

    int n = blockIdx.x * 64 + (t >> 2);
    if (n >= N) return;
    int c0 = (t & 3) * 16;
    const float4* xr = reinterpret_cast<const float4*>(x + (size_t)n * D_IN);

    float acc[16] = {};
    for (int k0 = 0; k0 < D_IN / 4; ++k0) {
        float4 xv = xr[k0];
        #pragma unroll
        for (int kk = 0; kk < 4; ++kk) {
            float xk = (kk == 0) ? xv.x : (kk == 1) ? xv.y : (kk == 2) ? xv.z : xv.w;
            const float* wrow = &sW[(4 * k0 + kk) * H_DIM + c0];
            #pragma unroll
            for (int c = 0; c < 4; ++c) {
                float4 wv = *reinterpret_cast<const float4*>(wrow + 4 * c);
                acc[4 * c + 0] += xk * wv.x;
                acc[4 * c + 1] += xk * wv.y;
                acc[4 * c + 2] += xk * wv.z;
                acc[4 * c + 3] += xk * wv.w;
            }
        }
    }
    float di = dinv[n];
    unsigned short* orow = h1s + (size_t)n * H_DIM + c0;
    #pragma unroll
    for (int c = 0; c < 4; ++c) {
        ushort4 u;
        u.x = f2bf(acc[4 * c + 0] * di);
        u.y = f2bf(acc[4 * c + 1] * di);
        u.z = f2bf(acc[4 * c + 2] * di);
        u.w = f2bf(acc[4 * c + 3] * di);
        *reinterpret_cast<ushort4*>(orow + 4 * c) = u;
    }
}

// ============ fused agg1 + gemm2: z stays in registers; writes h2s = bf16(dinv*(z@W2)) ============
// agg body = round-6 agg1_v3 (measured 53 us). After the xor-butterfly ALL 64 lanes hold the
// full sum for feature slice (lane&15)*4, so z never touches memory: broadcast via __shfl and
// multiply against W2 staged in LDS. Grid-stride (4096 blocks) bounds W2 reload traffic.
__global__ __launch_bounds__(256) void agg1g2_fused(const int* __restrict__ rows,
                                                    const int* __restrict__ csr,
                                                    const unsigned short* __restrict__ h1s,
                                                    const float* __restrict__ dinv,
                                                    const float* __restrict__ b1,
                                                    const float* __restrict__ W2,
                                                    unsigned short* __restrict__ h2s, int N) {
    __shared__ float sW2[H_DIM * D_OUT];    // 10 KB
    int t = threadIdx.x;
    for (int i = t; i < H_DIM * D_OUT / 4; i += 256)
        reinterpret_cast<float4*>(sW2)[i] = reinterpret_cast<const float4*>(W2)[i];
    __syncthreads();

    int wid  = t >> 6;
    int lane = t & 63;
    int e  = lane >> 4;            // edge slot 0..3
    int fl = (lane & 15) * 4;      // feature base (0..60)
    int lc = min(lane, D_OUT - 1); // clamped col for LDS reads (lanes >=40 compute garbage)

    for (int node = blockIdx.x * 4 + wid; node < N; node += gridDim.x * 4) {
        int ridx = node + (node >> BW_SHIFT);
        int s0 = __builtin_amdgcn_readfirstlane(rows[ridx]);
        int s1 = __builtin_amdgcn_readfirstlane(rows[ridx + 1]);

        float4 acc = make_float4(0.f, 0.f, 0.f, 0.f);
        for (int base = s0; base < s1; base += 64) {
            int cnt = min(64, s1 - base);                 // wave-uniform
            int myc = (lane < cnt) ? csr[base + lane] : 0;  // one coalesced load
            int j = 0;
            for (; j + 8 <= cnt; j += 8) {                // 8 independent gathers
                uint32 sa = (uint32)__shfl(myc, j + e);
                uint32 sb = (uint32)__shfl(myc, j + 4 + e);
                ushort4 ha = *reinterpret_cast<const ushort4*>(h1s + (size_t)(sa * H_DIM + fl));
                ushort4 hb = *reinterpret_cast<const ushort4*>(h1s + (size_t)(sb * H_DIM + fl));
                acc.x += bf2f(ha.x) + bf2f(hb.x);
                acc.y += bf2f(ha.y) + bf2f(hb.y);
                acc.z += bf2f(ha.z) + bf2f(hb.z);
                acc.w += bf2f(ha.w) + bf2f(hb.w);
            }
            for (; j < cnt; j += 4) {                     // tail (wave-uniform loop)
                int idx = j + e;
                uint32 sa = (uint32)__shfl(myc, min(idx, cnt - 1));
                if (idx < cnt) {
                    ushort4 hv = *reinterpret_cast<const ushort4*>(h1s + (size_t)(sa * H_DIM + fl));
                    acc.x += bf2f(hv.x); acc.y += bf2f(hv.y);
                    acc.z += bf2f(hv.z); acc.w += bf2f(hv.w);
                }
            }
        }
        // butterfly -> ALL lanes hold full sums for their feature slice
        acc.x += __shfl_xor(acc.x, 16); acc.y += __shfl_xor(acc.y, 16);
        acc.z += __shfl_xor(acc.z, 16); acc.w += __shfl_xor(acc.w, 16);
        acc.x += __shfl_xor(acc.x, 32); acc.y += __shfl_xor(acc.y, 32);
        acc.z += __shfl_xor(acc.z, 32); acc.w += __shfl_xor(acc.w, 32);

        // z (relu'd) in registers, every lane
        ushort4 sv = *reinterpret_cast<const ushort4*>(h1s + (size_t)node * H_DIM + fl);
        float4 bv = *reinterpret_cast<const float4*>(b1 + fl);
        float di = dinv[node];
        float4 z4;
        z4.x = fmaxf(0.f, di * (acc.x + bf2f(sv.x)) + bv.x);
        z4.y = fmaxf(0.f, di * (acc.y + bf2f(sv.y)) + bv.y);
        z4.z = fmaxf(0.f, di * (acc.z + bf2f(sv.z)) + bv.z);
        z4.w = fmaxf(0.f, di * (acc.w + bf2f(sv.w)) + bv.w);

        // gemm2: lane computes output col lc; z[4k0+kk] broadcast from lane k0
        float acc2 = 0.f;
        #pragma unroll
        for (int k0 = 0; k0 < H_DIM / 4; ++k0) {
            float zx = __shfl(z4.x, k0);
            float zy = __shfl(z4.y, k0);
            float zz = __shfl(z4.z, k0);
            float zw = __shfl(z4.w, k0);
            const float* wr = &sW2[4 * k0 * D_OUT + lc];
            acc2 += zx * wr[0] + zy * wr[D_OUT] + zz * wr[2 * D_OUT] + zw * wr[3 * D_OUT];
        }
        if (lane < D_OUT)
            h2s[(size_t)node * D_OUT + lane] = f2bf(acc2 * di);
    }
}

// ============ agg2_v4 + log_softmax (round-6 exact): 6 groups x 10 lanes, fast exp/log ============
__global__ __launch_bounds__(256) void agg2_v4(const int* __restrict__ rows,
                                               const int* __restrict__ csr,
                                               const unsigned short* __restrict__ h2s,
                                               const float* __restrict__ dinv,
                                               const float* __restrict__ b2,
                                               float* __restrict__ out, int N) {
    int node = blockIdx.x * 4 + (threadIdx.x >> 6);
    if (node >= N) return;
    int lane = threadIdx.x & 63;
    int g   = lane / 10;           // edge slot 0..5 (6 = idle lanes 60..63)
    int f10 = lane - g * 10;       // feature block 0..9
    int fl  = f10 * 4;             // short offset (0..36), 8B-aligned loads
    bool gact = g < 6;
    int ridx = node + (node >> BW_SHIFT);
    int s0 = __builtin_amdgcn_readfirstlane(rows[ridx]);
    int s1 = __builtin_amdgcn_readfirstlane(rows[ridx + 1]);

    float4 acc = make_float4(0.f, 0.f, 0.f, 0.f);
    for (int base = s0; base < s1; base += 64) {
        int cnt = min(64, s1 - base);
        int myc = (lane < cnt) ? csr[base + lane] : 0;
        int j = 0;
        for (; j + 12 <= cnt; j += 12) {              // 12 independent gathers
            uint32 sa = (uint32)__shfl(myc, min(j + g, 63));
            uint32 sb = (uint32)__shfl(myc, min(j + 6 + g, 63));
            if (gact) {
                ushort4 ha = *reinterpret_cast<const ushort4*>(h2s + (size_t)(sa * D_OUT + fl));
                ushort4 hb = *reinterpret_cast<const ushort4*>(h2s + (size_t)(sb * D_OUT + fl));
                acc.x += bf2f(ha.x) + bf2f(hb.x);
                acc.y += bf2f(ha.y) + bf2f(hb.y);
                acc.z += bf2f(ha.z) + bf2f(hb.z);
                acc.w += bf2f(ha.w) + bf2f(hb.w);
            }
        }
        for (; j < cnt; j += 6) {
            int idx = j + g;
            uint32 sa = (uint32)__shfl(myc, min(idx, cnt - 1));
            if (gact && idx < cnt) {
                ushort4 hv = *reinterpret_cast<const ushort4*>(h2s + (size_t)(sa * D_OUT + fl));
                acc.x += bf2f(hv.x); acc.y += bf2f(hv.y);
                acc.z += bf2f(hv.z); acc.w += bf2f(hv.w);
            }
        }
    }
    // combine 6 edge-slot groups: +30, then +10/+20
    acc.x += __shfl(acc.x, min(lane + 30, 63));
    acc.y += __shfl(acc.y, min(lane + 30, 63));
    acc.z += __shfl(acc.z, min(lane + 30, 63));
    acc.w += __shfl(acc.w, min(lane + 30, 63));
    acc.x += __shfl(acc.x, min(lane + 10, 63)) + __shfl(acc.x, min(lane + 20, 63));
    acc.y += __shfl(acc.y, min(lane + 10, 63)) + __shfl(acc.y, min(lane + 20, 63));
    acc.z += __shfl(acc.z, min(lane + 10, 63)) + __shfl(acc.z, min(lane + 20, 63));
    acc.w += __shfl(acc.w, min(lane + 10, 63)) + __shfl(acc.w, min(lane + 20, 63));

    bool act = lane < 10;
    float v0 = -INFINITY, v1 = -INFINITY, v2 = -INFINITY, v3 = -INFINITY;
    if (act) {
        ushort4 sv = *reinterpret_cast<const ushort4*>(h2s + (size_t)node * D_OUT + fl);
        float4 bv = *reinterpret_cast<const float4*>(b2 + fl);
        float di = dinv[node];
        v0 = di * (acc.x + bf2f(sv.x)) + bv.x;
        v1 = di * (acc.y + bf2f(sv.y)) + bv.y;
        v2 = di * (acc.z + bf2f(sv.z)) + bv.z;
        v3 = di * (acc.w + bf2f(sv.w)) + bv.w;
    }
    float mm = act ? fmaxf(fmaxf(v0, v1), fmaxf(v2, v3)) : -INFINITY;
    for (int off = 32; off > 0; off >>= 1) mm = fmaxf(mm, __shfl_xor(mm, off));
    float es = act ? (__expf(v0 - mm) + __expf(v1 - mm) + __expf(v2 - mm) + __expf(v3 - mm)) : 0.f;
    for (int off = 32; off > 0; off >>= 1) es += __shfl_xor(es, off);
    float lse = __logf(es);
    if (act) {
        float4 o = make_float4(v0 - mm - lse, v1 - mm - lse, v2 - mm - lse, v3 - mm - lse);
        *reinterpret_cast<float4*>(out + (size_t)node * D_OUT + fl) = o;
    }
}

extern "C" void kernel_launch(void* const* d_in, const int* in_sizes, int n_in,
                              void* d_out, int out_size, void* d_ws, size_t ws_size,
                              hipStream_t stream) {
    const float* x  = (const float*)d_in[0];
    const int*   ei = (const int*)d_in[1];
    const float* W1 = (const float*)d_in[2];
    const float* b1 = (const float*)d_in[3];
    const float* W2 = (const float*)d_in[4];
    const float* b2 = (const float*)d_in[5];
    float* out = (float*)d_out;

    int N = in_sizes[0] / D_IN;
    int E = in_sizes[1] / 2;
    const int* src = ei;
    const int* dst = ei + E;
    int NBUCK = (N + BW_NODES - 1) / BW_NODES;   // 196 for N=100K (<=1024)

    // ---- workspace layout (~29 MB). h2s is a SEPARATE buffer: the fused kernel
    // reads h1s (other nodes' rows) while writing h2s -> must not alias. ----
    char* p = (char*)d_ws;
    int*   gcursor = (int*)p;  p += 4096;
    int*   rows    = (int*)p;  p += ((size_t)NBUCK * 513 + 64) * 4;
    float* dinv    = (float*)p; p += (((size_t)N + 63) & ~(size_t)63) * 4;
    uint32* binned = (uint32*)p; p += (size_t)NBUCK * BUCKET_CAP * 4;   // becomes csr in-place
    unsigned short* h1s = (unsigned short*)p; p += (size_t)N * H_DIM * 2;
    unsigned short* h2s = (unsigned short*)p; p += (((size_t)N * D_OUT * 2 + 255) & ~(size_t)255);

    int binA_blocks = (E + BINA_CHUNK - 1) / BINA_CHUNK;

    // ---- CSR build: fixed-capacity buckets ----
    cursor_init_kernel<<<(NBUCK + 255) / 256, 256, 0, stream>>>(gcursor, NBUCK);
    binA_scatter_kernel<<<binA_blocks, 256, 0, stream>>>(src, dst, gcursor, binned, E, NBUCK);
    phaseB_kernel<<<NBUCK, 256, 0, stream>>>(binned, gcursor, rows, dinv, N);
    int* csr = (int*)binned;

    // ---- layer 1 ----
    gemm1_tn4<<<(N + 63) / 64, 256, 0, stream>>>(x, W1, dinv, h1s, N);

    // ---- fused agg1 + gemm2 (z never hits memory) ----
    int fgrid = min((N + 3) / 4, 4096);
    agg1g2_fused<<<fgrid, 256, 0, stream>>>(rows, csr, h1s, dinv, b1, W2, h2s, N);

    // ---- layer 2 aggregation + log_softmax ----
    agg2_v4<<<(N + 3) / 4, 256, 0, stream>>>(rows, csr, h2s, dinv, b2, out, N);
}